// Round 2
// baseline (558.140 us; speedup 1.0000x reference)
//
#include <hip/hip_runtime.h>
#include <cstdint>
#include <cstddef>

#define HH 12
#define DHD 64
#define BB 64
#define SS 512
#define DD 768
#define PP 256
#define N3 2304

typedef __attribute__((ext_vector_type(8))) short bf16x8_t;
typedef __attribute__((ext_vector_type(4))) float f32x4_t;

__constant__ float c_slopes[12] = {
  0.5f, 0.25f, 0.125f, 0.0625f, 0.03125f, 0.015625f, 0.0078125f, 0.00390625f,
  0.70710678118654752f, 0.35355339059327376f, 0.17677669529663688f, 0.08838834764831844f
};

__device__ __forceinline__ ushort f2bf(float f) {
  union { float f; unsigned u; } v; v.f = f;
  unsigned r = v.u + 0x7fffu + ((v.u >> 16) & 1u);  // RNE
  return (ushort)(r >> 16);
}
__device__ __forceinline__ float bf2f(ushort u) {
  union { unsigned u; float f; } v; v.u = ((unsigned)u) << 16;
  return v.f;
}

// ---------------- cast hidden_states fp32 -> bf16 ----------------
__global__ void cast_hs_kernel(const float* __restrict__ in, ushort* __restrict__ out) {
  int i = blockIdx.x * 256 + threadIdx.x;          // exactly 6291456 float4 groups
  float4 v = ((const float4*)in)[i];
  ushort4 o;
  o.x = f2bf(v.x); o.y = f2bf(v.y); o.z = f2bf(v.z); o.w = f2bf(v.w);
  ((ushort4*)out)[i] = o;
}

// ---------------- transpose + cast W (768x2304) -> Wt bf16 (2304x768) ----------------
__global__ void transpose_w_kernel(const float* __restrict__ W, ushort* __restrict__ Wt) {
  __shared__ float tile[32][33];
  int n0 = blockIdx.x * 32, k0 = blockIdx.y * 32;
  int tx = threadIdx.x & 31, ty = threadIdx.x >> 5;
  for (int r = ty; r < 32; r += 8) tile[r][tx] = W[(size_t)(k0 + r) * N3 + n0 + tx];
  __syncthreads();
  for (int r = ty; r < 32; r += 8) Wt[(size_t)(n0 + r) * DD + k0 + tx] = f2bf(tile[tx][r]);
}

// ---------------- GEMM: qkv[m][n] = (A[m][:] . W[:][n] + bias[n]) * mask[m], bf16 out ----------------
__global__ __launch_bounds__(256) void gemm_qkv_kernel(
    const ushort* __restrict__ A, const ushort* __restrict__ Wt,
    const float* __restrict__ bias, const int* __restrict__ mask,
    ushort* __restrict__ qkv) {
  __shared__ __align__(16) ushort As[128][40];
  __shared__ __align__(16) ushort Bs[128][40];
  const int bm = blockIdx.x * 128;
  const int bn = blockIdx.y * 128;
  const int tid = threadIdx.x;
  const int lane = tid & 63;
  const int wave = tid >> 6;
  const int wm = (wave & 1) * 64;
  const int wn = (wave >> 1) * 64;
  const int fr = lane & 15, quad = lane >> 4;
  const int lrow = tid >> 1;
  const int lkoff = (tid & 1) * 16;
  const ushort* Ag = A + (size_t)(bm + lrow) * DD + lkoff;
  const ushort* Bg = Wt + (size_t)(bn + lrow) * DD + lkoff;
  f32x4_t acc[4][4];
  for (int i = 0; i < 4; i++)
    for (int j = 0; j < 4; j++) acc[i][j] = (f32x4_t){0.f, 0.f, 0.f, 0.f};
  for (int k0 = 0; k0 < DD; k0 += 32) {
    float4 a0 = *(const float4*)(Ag + k0);
    float4 a1 = *(const float4*)(Ag + k0 + 8);
    float4 b0 = *(const float4*)(Bg + k0);
    float4 b1 = *(const float4*)(Bg + k0 + 8);
    __syncthreads();
    *(float4*)&As[lrow][lkoff]     = a0;
    *(float4*)&As[lrow][lkoff + 8] = a1;
    *(float4*)&Bs[lrow][lkoff]     = b0;
    *(float4*)&Bs[lrow][lkoff + 8] = b1;
    __syncthreads();
    bf16x8_t af[4], bfv[4];
    for (int mt = 0; mt < 4; mt++) af[mt]  = *(const bf16x8_t*)&As[wm + mt*16 + fr][quad*8];
    for (int nt = 0; nt < 4; nt++) bfv[nt] = *(const bf16x8_t*)&Bs[wn + nt*16 + fr][quad*8];
    for (int mt = 0; mt < 4; mt++)
      for (int nt = 0; nt < 4; nt++)
        acc[mt][nt] = __builtin_amdgcn_mfma_f32_16x16x32_bf16(af[mt], bfv[nt], acc[mt][nt], 0, 0, 0);
  }
  for (int mt = 0; mt < 4; mt++) {
    const int mbase = bm + wm + mt*16 + quad*4;
    for (int r = 0; r < 4; r++) {
      const int m = mbase + r;
      const float mval = (float)mask[m];
      for (int nt = 0; nt < 4; nt++) {
        const int n = bn + wn + nt*16 + fr;
        float v = (acc[mt][nt][r] + bias[n]) * mval;
        qkv[(size_t)m * N3 + n] = f2bf(v);
      }
    }
  }
}

// ---------------- pool: q_pooled, residual, new_mask ----------------
__global__ void pool_kernel(const ushort* __restrict__ qkv, const int* __restrict__ mask,
                            float* __restrict__ out, ushort* __restrict__ qp) {
  int idx = blockIdx.x * 256 + threadIdx.x;       // 64*256*192 total
  int d4 = idx % 192;
  int bp = idx / 192;
  int b = bp >> 8, p = bp & 255;
  int m0 = mask[b*512 + 2*p], m1 = mask[b*512 + 2*p + 1];
  int ms = m0 + m1;
  float inv = 1.0f / (float)(ms < 1 ? 1 : ms);
  const ushort* r0 = qkv + (size_t)(b*512 + 2*p) * N3 + d4*4;
  ushort4 x0 = *(const ushort4*)r0;
  ushort4 x1 = *(const ushort4*)(r0 + N3);
  float y0 = (bf2f(x0.x) + bf2f(x1.x)) * inv;
  float y1 = (bf2f(x0.y) + bf2f(x1.y)) * inv;
  float y2 = (bf2f(x0.z) + bf2f(x1.z)) * inv;
  float y3 = (bf2f(x0.w) + bf2f(x1.w)) * inv;
  float4 y = {y0, y1, y2, y3};
  *(float4*)(out + 12599296 + (size_t)bp * 768 + d4*4) = y;    // residual_query (==0 when masked)
  ushort4 q8;                                                   // fold 1/sqrt(DH)=1/8 into bf16 q
  q8.x = f2bf(y0 * 0.125f); q8.y = f2bf(y1 * 0.125f);
  q8.z = f2bf(y2 * 0.125f); q8.w = f2bf(y3 * 0.125f);
  *(ushort4*)(qp + (size_t)bp * 768 + d4*4) = q8;
  if (d4 == 0) out[12582912 + bp] = (ms > 0) ? 1.0f : 0.0f;     // new_mask
}

// ---------------- attention: per (p-tile 16, h, b) ----------------
__global__ __launch_bounds__(256) void attn_kernel(
    const ushort* __restrict__ qkv, const ushort* __restrict__ qp,
    const int* __restrict__ mask, const float* __restrict__ nmask,
    float* __restrict__ outA) {
  __shared__ __align__(16) ushort q_lds[16][72];
  __shared__ __align__(16) float  sc[16][520];       // later aliased as bf16 P rows
  __shared__ __align__(16) ushort k_st[4][16][72];   // per-wave K staging
  __shared__ __align__(16) ushort vt_st[4][16][40];  // per-wave V^T staging
  const int pt = blockIdx.x, h = blockIdx.y, b = blockIdx.z;
  const int pbase = pt * 16;
  const int tid = threadIdx.x, wave = tid >> 6, lane = tid & 63;
  const int fr = lane & 15, quad = lane >> 4;
  if (tid < 128) {                       // 16 rows x 64 cols, 8 cols per thread
    int r = tid >> 3, cseg = (tid & 7) * 8;
    *(float4*)&q_lds[r][cseg] =
        *(const float4*)(qp + (size_t)(b*256 + pbase + r) * 768 + h*64 + cseg);
  }
  __syncthreads();
  bf16x8_t a0 = *(const bf16x8_t*)&q_lds[fr][quad*8];
  bf16x8_t a1 = *(const bf16x8_t*)&q_lds[fr][32 + quad*8];
  // ---- QK^T: wave handles s in [wave*128, wave*128+128) ----
  const ushort* Kb = qkv + (size_t)(b*512) * N3 + 768 + h*64;
  for (int st = 0; st < 8; st++) {
    int sb = wave*128 + st*16;
    {
      int r = lane >> 2, c = (lane & 3) * 16;
      const ushort* src = Kb + (size_t)(sb + r) * N3 + c;
      *(float4*)&k_st[wave][r][c]     = *(const float4*)src;
      *(float4*)&k_st[wave][r][c + 8] = *(const float4*)(src + 8);
    }
    bf16x8_t b0 = *(const bf16x8_t*)&k_st[wave][fr][quad*8];
    bf16x8_t b1 = *(const bf16x8_t*)&k_st[wave][fr][32 + quad*8];
    f32x4_t d = (f32x4_t){0.f, 0.f, 0.f, 0.f};
    d = __builtin_amdgcn_mfma_f32_16x16x32_bf16(a0, b0, d, 0, 0, 0);
    d = __builtin_amdgcn_mfma_f32_16x16x32_bf16(a1, b1, d, 0, 0, 0);
    for (int r = 0; r < 4; r++) sc[quad*4 + r][sb + fr] = d[r];
  }
  __syncthreads();
  // ---- softmax + bias (ALiBi + pair mask); P -> bf16 aliased over sc rows ----
  const float slope = c_slopes[h];
  int kvalid[8];
  for (int j = 0; j < 8; j++) kvalid[j] = mask[b*512 + lane + j*64];
  for (int i = 0; i < 4; i++) {
    int r = wave*4 + i;
    int p = pbase + r;
    bool rowv = nmask[b*256 + p] > 0.5f;
    float vals[8];
    float mx = -3.0e38f;
    for (int j = 0; j < 8; j++) {
      int s = lane + j*64;
      float v = sc[r][s];
      v += ((rowv && kvalid[j]) ? 0.0f : -10000.0f) - slope * fabsf((float)(s - p));
      vals[j] = v;
      mx = fmaxf(mx, v);
    }
    for (int off = 32; off > 0; off >>= 1) mx = fmaxf(mx, __shfl_xor(mx, off, 64));
    float sum = 0.f;
    for (int j = 0; j < 8; j++) { vals[j] = __expf(vals[j] - mx); sum += vals[j]; }
    for (int off = 32; off > 0; off >>= 1) sum += __shfl_xor(sum, off, 64);
    float inv = 1.0f / sum;
    ushort* prow = (ushort*)&sc[r][0];
    for (int j = 0; j < 8; j++) prow[lane + j*64] = f2bf(vals[j] * inv);
  }
  __syncthreads();
  // ---- P.V: wave handles d-range [wave*16, wave*16+16) ----
  const ushort* Vb = qkv + (size_t)(b*512) * N3 + 1536 + h*64 + wave*16;
  f32x4_t acc = (f32x4_t){0.f, 0.f, 0.f, 0.f};
  for (int ks = 0; ks < 16; ks++) {
    int sb = ks * 32;
    {
      int s = lane >> 1, dh = (lane & 1) * 8;
      const ushort* src = Vb + (size_t)(sb + s) * N3 + dh;
      ushort tmp[8];
      *(float4*)tmp = *(const float4*)src;
      for (int j = 0; j < 8; j++) vt_st[wave][dh + j][s] = tmp[j];
    }
    const ushort* prow = (const ushort*)&sc[fr][0];
    bf16x8_t ap = *(const bf16x8_t*)&prow[sb + quad*8];
    bf16x8_t bv = *(const bf16x8_t*)&vt_st[wave][fr][quad*8];
    acc = __builtin_amdgcn_mfma_f32_16x16x32_bf16(ap, bv, acc, 0, 0, 0);
  }
  for (int r = 0; r < 4; r++) {
    int p = pbase + quad*4 + r;
    float nm = nmask[b*256 + p];
    outA[(size_t)(b*256 + p) * 768 + h*64 + wave*16 + fr] = acc[r] * nm;
  }
}

extern "C" void kernel_launch(void* const* d_in, const int* in_sizes, int n_in,
                              void* d_out, int out_size, void* d_ws, size_t ws_size,
                              hipStream_t stream) {
  const float* hs   = (const float*)d_in[0];
  const int*   mask = (const int*)d_in[1];
  const float* W    = (const float*)d_in[2];
  const float* bias = (const float*)d_in[3];
  float* out = (float*)d_out;
  char* ws = (char*)d_ws;
  // ws layout (bytes): A_bf16 [0, 50331648) ; Wt [50331648, 53870592) ;
  //                    qkv_bf16 [53870592, 204865536). qp aliases A (A dead after GEMM).
  ushort* A   = (ushort*)(ws);
  ushort* Wt  = (ushort*)(ws + 50331648);
  ushort* qkv = (ushort*)(ws + 53870592);
  ushort* qp  = (ushort*)(ws);

  hipLaunchKernelGGL(cast_hs_kernel, dim3(24576), dim3(256), 0, stream, hs, A);
  hipLaunchKernelGGL(transpose_w_kernel, dim3(72, 24), dim3(256), 0, stream, W, Wt);
  hipLaunchKernelGGL(gemm_qkv_kernel, dim3(256, 18), dim3(256), 0, stream, A, Wt, bias, mask, qkv);
  hipLaunchKernelGGL(pool_kernel, dim3(12288), dim3(256), 0, stream, qkv, mask, out, qp);
  hipLaunchKernelGGL(attn_kernel, dim3(16, 12, 64), dim3(256), 0, stream,
                     qkv, qp, mask, out + 12582912, out);
}

// Round 3
// 535.842 us; speedup vs baseline: 1.0416x; 1.0416x over previous
//
#include <hip/hip_runtime.h>
#include <cstdint>
#include <cstddef>

#define HH 12
#define DHD 64
#define BB 64
#define SS 512
#define DD 768
#define PP 256
#define N3 2304

typedef __attribute__((ext_vector_type(8))) short bf16x8_t;
typedef __attribute__((ext_vector_type(4))) float f32x4_t;

__constant__ float c_slopes[12] = {
  0.5f, 0.25f, 0.125f, 0.0625f, 0.03125f, 0.015625f, 0.0078125f, 0.00390625f,
  0.70710678118654752f, 0.35355339059327376f, 0.17677669529663688f, 0.08838834764831844f
};

__device__ __forceinline__ ushort f2bf(float f) {
  union { float f; unsigned u; } v; v.f = f;
  unsigned r = v.u + 0x7fffu + ((v.u >> 16) & 1u);  // RNE
  return (ushort)(r >> 16);
}
__device__ __forceinline__ float bf2f(ushort u) {
  union { unsigned u; float f; } v; v.u = ((unsigned)u) << 16;
  return v.f;
}
__device__ __forceinline__ void gload_lds16(const ushort* g, ushort* l) {
  __builtin_amdgcn_global_load_lds(
      (const __attribute__((address_space(1))) void*)g,
      (__attribute__((address_space(3))) void*)l, 16, 0, 0);
}

// ---------------- cast hidden_states fp32 -> bf16 ----------------
__global__ void cast_hs_kernel(const float* __restrict__ in, ushort* __restrict__ out) {
  int i = blockIdx.x * 256 + threadIdx.x;          // exactly 6291456 float4 groups
  float4 v = ((const float4*)in)[i];
  ushort4 o;
  o.x = f2bf(v.x); o.y = f2bf(v.y); o.z = f2bf(v.z); o.w = f2bf(v.w);
  ((ushort4*)out)[i] = o;
}

// ---------------- transpose + cast W (768x2304) -> Wt bf16 (2304x768) ----------------
__global__ void transpose_w_kernel(const float* __restrict__ W, ushort* __restrict__ Wt) {
  __shared__ float tile[32][33];
  int n0 = blockIdx.x * 32, k0 = blockIdx.y * 32;
  int tx = threadIdx.x & 31, ty = threadIdx.x >> 5;
  for (int r = ty; r < 32; r += 8) tile[r][tx] = W[(size_t)(k0 + r) * N3 + n0 + tx];
  __syncthreads();
  for (int r = ty; r < 32; r += 8) Wt[(size_t)(n0 + r) * DD + k0 + tx] = f2bf(tile[tx][r]);
}

// ---------------- GEMM (m97 structure): qkv = (A.W + bias) * mask, bf16 out ----------------
// LDS layout is lane-linear (unpadded [128][32]) because global_load_lds scatters
// each lane's 16B at wave-uniform-base + lane*16.
__global__ __launch_bounds__(256) void gemm_qkv_kernel(
    const ushort* __restrict__ A, const ushort* __restrict__ Wt,
    const float* __restrict__ bias, const int* __restrict__ mask,
    ushort* __restrict__ qkv) {
  __shared__ __align__(16) ushort As[128 * 32];
  __shared__ __align__(16) ushort Bs[128 * 32];
  const int bm = blockIdx.x * 128;
  const int bn = blockIdx.y * 128;
  const int tid = threadIdx.x;
  const int lane = tid & 63;
  const int wave = tid >> 6;
  const int wm = (wave & 1) * 64;
  const int wn = (wave >> 1) * 64;
  const int fr = lane & 15, quad = lane >> 4;
  // staging: instr i (0,1) of this wave covers tile rows [wave*32 + i*16 + (lane>>2)],
  // k-cols (lane&3)*8 .. +8   (seg = wave*128 + i*64 + lane ; LDS byte = seg*16)
  const int srow = wave * 32 + (lane >> 2);
  const int scol = (lane & 3) * 8;
  const ushort* Ag0 = A  + (size_t)(bm + srow) * DD + scol;
  const ushort* Ag1 = Ag0 + 16 * DD;
  const ushort* Bg0 = Wt + (size_t)(bn + srow) * DD + scol;
  const ushort* Bg1 = Bg0 + 16 * DD;
  ushort* AsW0 = As + (wave * 2 + 0) * 512;   // 1024B per wave-instr
  ushort* AsW1 = As + (wave * 2 + 1) * 512;
  ushort* BsW0 = Bs + (wave * 2 + 0) * 512;
  ushort* BsW1 = Bs + (wave * 2 + 1) * 512;

  f32x4_t acc[4][4];
  for (int i = 0; i < 4; i++)
    for (int j = 0; j < 4; j++) acc[i][j] = (f32x4_t){0.f, 0.f, 0.f, 0.f};

  for (int k0 = 0; k0 < DD; k0 += 32) {
    gload_lds16(Ag0 + k0, AsW0);
    gload_lds16(Ag1 + k0, AsW1);
    gload_lds16(Bg0 + k0, BsW0);
    gload_lds16(Bg1 + k0, BsW1);
    __syncthreads();
    bf16x8_t af[4], bfv[4];
    for (int mt = 0; mt < 4; mt++) af[mt]  = *(const bf16x8_t*)&As[(wm + mt*16 + fr) * 32 + quad*8];
    for (int nt = 0; nt < 4; nt++) bfv[nt] = *(const bf16x8_t*)&Bs[(wn + nt*16 + fr) * 32 + quad*8];
    for (int mt = 0; mt < 4; mt++)
      for (int nt = 0; nt < 4; nt++)
        acc[mt][nt] = __builtin_amdgcn_mfma_f32_16x16x32_bf16(af[mt], bfv[nt], acc[mt][nt], 0, 0, 0);
    __syncthreads();
  }
  for (int mt = 0; mt < 4; mt++) {
    const int mbase = bm + wm + mt*16 + quad*4;
    for (int r = 0; r < 4; r++) {
      const int m = mbase + r;
      const float mval = (float)mask[m];
      for (int nt = 0; nt < 4; nt++) {
        const int n = bn + wn + nt*16 + fr;
        float v = (acc[mt][nt][r] + bias[n]) * mval;
        qkv[(size_t)m * N3 + n] = f2bf(v);
      }
    }
  }
}

// ---------------- pool: q_pooled, residual, new_mask ----------------
__global__ void pool_kernel(const ushort* __restrict__ qkv, const int* __restrict__ mask,
                            float* __restrict__ out, ushort* __restrict__ qp) {
  int idx = blockIdx.x * 256 + threadIdx.x;       // 64*256*192 total
  int d4 = idx % 192;
  int bp = idx / 192;
  int b = bp >> 8, p = bp & 255;
  int m0 = mask[b*512 + 2*p], m1 = mask[b*512 + 2*p + 1];
  int ms = m0 + m1;
  float inv = 1.0f / (float)(ms < 1 ? 1 : ms);
  const ushort* r0 = qkv + (size_t)(b*512 + 2*p) * N3 + d4*4;
  ushort4 x0 = *(const ushort4*)r0;
  ushort4 x1 = *(const ushort4*)(r0 + N3);
  float y0 = (bf2f(x0.x) + bf2f(x1.x)) * inv;
  float y1 = (bf2f(x0.y) + bf2f(x1.y)) * inv;
  float y2 = (bf2f(x0.z) + bf2f(x1.z)) * inv;
  float y3 = (bf2f(x0.w) + bf2f(x1.w)) * inv;
  float4 y = {y0, y1, y2, y3};
  *(float4*)(out + 12599296 + (size_t)bp * 768 + d4*4) = y;    // residual_query (==0 when masked)
  ushort4 q8;                                                   // fold 1/sqrt(DH)=1/8 into bf16 q
  q8.x = f2bf(y0 * 0.125f); q8.y = f2bf(y1 * 0.125f);
  q8.z = f2bf(y2 * 0.125f); q8.w = f2bf(y3 * 0.125f);
  *(ushort4*)(qp + (size_t)bp * 768 + d4*4) = q8;
  if (d4 == 0) out[12582912 + bp] = (ms > 0) ? 1.0f : 0.0f;     // new_mask
}

// ---------------- attention: per (p-tile 16, h, b) ----------------
__global__ __launch_bounds__(256) void attn_kernel(
    const ushort* __restrict__ qkv, const ushort* __restrict__ qp,
    const int* __restrict__ mask, const float* __restrict__ nmask,
    float* __restrict__ outA) {
  __shared__ __align__(16) ushort q_lds[16][72];
  __shared__ __align__(16) float  sc[16][520];       // later aliased as bf16 P rows
  __shared__ __align__(16) ushort k_st[4][16][72];   // per-wave K staging
  __shared__ __align__(16) ushort vt_st[4][16][40];  // per-wave V^T staging
  const int pt = blockIdx.x, h = blockIdx.y, b = blockIdx.z;
  const int pbase = pt * 16;
  const int tid = threadIdx.x, wave = tid >> 6, lane = tid & 63;
  const int fr = lane & 15, quad = lane >> 4;
  if (tid < 128) {                       // 16 rows x 64 cols, 8 cols per thread
    int r = tid >> 3, cseg = (tid & 7) * 8;
    *(float4*)&q_lds[r][cseg] =
        *(const float4*)(qp + (size_t)(b*256 + pbase + r) * 768 + h*64 + cseg);
  }
  __syncthreads();
  bf16x8_t a0 = *(const bf16x8_t*)&q_lds[fr][quad*8];
  bf16x8_t a1 = *(const bf16x8_t*)&q_lds[fr][32 + quad*8];
  // ---- QK^T: wave handles s in [wave*128, wave*128+128), prefetched pipeline ----
  const ushort* Kb = qkv + (size_t)(b*512) * N3 + 768 + h*64;
  const int kr = lane >> 2, kc = (lane & 3) * 16;
  const ushort* Ksrc = Kb + (size_t)(wave*128 + kr) * N3 + kc;
  float4 kcur0 = *(const float4*)(Ksrc);
  float4 kcur1 = *(const float4*)(Ksrc + 8);
  for (int st = 0; st < 8; st++) {
    int sb = wave*128 + st*16;
    float4 knxt0, knxt1;
    if (st < 7) {
      knxt0 = *(const float4*)(Ksrc + (size_t)(st+1)*16*N3);
      knxt1 = *(const float4*)(Ksrc + (size_t)(st+1)*16*N3 + 8);
    }
    *(float4*)&k_st[wave][kr][kc]     = kcur0;
    *(float4*)&k_st[wave][kr][kc + 8] = kcur1;
    bf16x8_t b0 = *(const bf16x8_t*)&k_st[wave][fr][quad*8];
    bf16x8_t b1 = *(const bf16x8_t*)&k_st[wave][fr][32 + quad*8];
    f32x4_t d = (f32x4_t){0.f, 0.f, 0.f, 0.f};
    d = __builtin_amdgcn_mfma_f32_16x16x32_bf16(a0, b0, d, 0, 0, 0);
    d = __builtin_amdgcn_mfma_f32_16x16x32_bf16(a1, b1, d, 0, 0, 0);
    for (int r = 0; r < 4; r++) sc[quad*4 + r][sb + fr] = d[r];
    kcur0 = knxt0; kcur1 = knxt1;
  }
  __syncthreads();
  // ---- softmax + bias (ALiBi + pair mask); P -> bf16 aliased over sc rows ----
  const float slope = c_slopes[h];
  int kvalid[8];
  for (int j = 0; j < 8; j++) kvalid[j] = mask[b*512 + lane + j*64];
  for (int i = 0; i < 4; i++) {
    int r = wave*4 + i;
    int p = pbase + r;
    bool rowv = nmask[b*256 + p] > 0.5f;
    float vals[8];
    float mx = -3.0e38f;
    for (int j = 0; j < 8; j++) {
      int s = lane + j*64;
      float v = sc[r][s];
      v += ((rowv && kvalid[j]) ? 0.0f : -10000.0f) - slope * fabsf((float)(s - p));
      vals[j] = v;
      mx = fmaxf(mx, v);
    }
    for (int off = 32; off > 0; off >>= 1) mx = fmaxf(mx, __shfl_xor(mx, off, 64));
    float sum = 0.f;
    for (int j = 0; j < 8; j++) { vals[j] = __expf(vals[j] - mx); sum += vals[j]; }
    for (int off = 32; off > 0; off >>= 1) sum += __shfl_xor(sum, off, 64);
    float inv = 1.0f / sum;
    ushort* prow = (ushort*)&sc[r][0];
    for (int j = 0; j < 8; j++) prow[lane + j*64] = f2bf(vals[j] * inv);
  }
  __syncthreads();
  // ---- P.V: wave handles d-range [wave*16, wave*16+16), prefetched pipeline ----
  const ushort* Vb = qkv + (size_t)(b*512) * N3 + 1536 + h*64 + wave*16;
  const int vs = lane >> 1, vd8 = (lane & 1) * 8;
  const ushort* Vsrc = Vb + (size_t)vs * N3 + vd8;
  f32x4_t acc = (f32x4_t){0.f, 0.f, 0.f, 0.f};
  float4 vcur = *(const float4*)(Vsrc);
  for (int ks = 0; ks < 16; ks++) {
    int sb = ks * 32;
    float4 vnxt;
    if (ks < 15) vnxt = *(const float4*)(Vsrc + (size_t)(ks+1)*32*N3);
    {
      ushort tmp[8];
      *(float4*)tmp = vcur;
      for (int j = 0; j < 8; j++) vt_st[wave][vd8 + j][vs] = tmp[j];
    }
    const ushort* prow = (const ushort*)&sc[fr][0];
    bf16x8_t ap = *(const bf16x8_t*)&prow[sb + quad*8];
    bf16x8_t bv = *(const bf16x8_t*)&vt_st[wave][fr][quad*8];
    acc = __builtin_amdgcn_mfma_f32_16x16x32_bf16(ap, bv, acc, 0, 0, 0);
    vcur = vnxt;
  }
  for (int r = 0; r < 4; r++) {
    int p = pbase + quad*4 + r;
    float nm = nmask[b*256 + p];
    outA[(size_t)(b*256 + p) * 768 + h*64 + wave*16 + fr] = acc[r] * nm;
  }
}

extern "C" void kernel_launch(void* const* d_in, const int* in_sizes, int n_in,
                              void* d_out, int out_size, void* d_ws, size_t ws_size,
                              hipStream_t stream) {
  const float* hs   = (const float*)d_in[0];
  const int*   mask = (const int*)d_in[1];
  const float* W    = (const float*)d_in[2];
  const float* bias = (const float*)d_in[3];
  float* out = (float*)d_out;
  char* ws = (char*)d_ws;
  // ws layout (bytes): A_bf16 [0, 50331648) ; Wt [50331648, 53870592) ;
  //                    qkv_bf16 [53870592, 204865536). qp aliases A (A dead after GEMM).
  ushort* A   = (ushort*)(ws);
  ushort* Wt  = (ushort*)(ws + 50331648);
  ushort* qkv = (ushort*)(ws + 53870592);
  ushort* qp  = (ushort*)(ws);

  hipLaunchKernelGGL(cast_hs_kernel, dim3(24576), dim3(256), 0, stream, hs, A);
  hipLaunchKernelGGL(transpose_w_kernel, dim3(72, 24), dim3(256), 0, stream, W, Wt);
  hipLaunchKernelGGL(gemm_qkv_kernel, dim3(256, 18), dim3(256), 0, stream, A, Wt, bias, mask, qkv);
  hipLaunchKernelGGL(pool_kernel, dim3(12288), dim3(256), 0, stream, qkv, mask, out, qp);
  hipLaunchKernelGGL(attn_kernel, dim3(16, 12, 64), dim3(256), 0, stream,
                     qkv, qp, mask, out + 12582912, out);
}